// Round 2
// baseline (93.067 us; speedup 1.0000x reference)
//
#include <hip/hip_runtime.h>
#include <math.h>

// FractalFeatureLayer: Petrosian-style fractal dimension over 5 dyadic scales.
// x: (B=64, C=64, T=4096) fp32 -> out: (B, C, 57) fp32.
//
// zc per window = range-sum of indicator c[i] = ((x[i+1]-x[i])*(x[i+2]-x[i+1]) < 0),
// window boundaries all multiples of 128 -> 128-wide segment sums (ballot half-mask
// popcounts, no LDS staging of x) + 33-entry prefix, with <=2 boundary corrections
// per window (re-read 4 floats from global, L2-hit).
//
// R2: removed 16KB LDS round trip + 48 ds_read_b32/thread + 1 barrier vs R1.
// Each thread: 4x global_load_dwordx4, indicators from registers + __shfl_down
// neighbors (lane 63 patches the 2 cross-wave floats from global).

constexpr int TLEN = 4096;
constexpr int NW   = 57;   // 1+3+7+15+31 windows

__global__ __launch_bounds__(256) void pfd_kernel(const float* __restrict__ x,
                                                  float* __restrict__ out) {
    __shared__ int wc[32];     // per-128-float-segment indicator counts
    __shared__ int pseg[33];   // exclusive prefix over segments

    const int tid  = threadIdx.x;
    const int row  = blockIdx.x;            // flattened (b*C + c)
    const int wave = tid >> 6;
    const int lane = tid & 63;
    const size_t base = (size_t)row * TLEN;
    const float* __restrict__ g = x + base;
    const float4* __restrict__ gv = reinterpret_cast<const float4*>(g);

#pragma unroll
    for (int k = 0; k < 4; ++k) {
        const int q    = (k << 8) + tid;    // float4 index within row
        const int fidx = q << 2;            // first float index of this lane's quad
        const float4 v = gv[q];

        // neighbor floats x[fidx+4], x[fidx+5] from next lane (or global for lane 63)
        float nx = __shfl_down(v.x, 1);
        float ny = __shfl_down(v.y, 1);
        if (lane == 63) {
            if (fidx + 4 < TLEN) {          // else indicators needing them are invalid
                nx = g[fidx + 4];
                ny = g[fidx + 5];
            } else {
                nx = 0.0f; ny = 0.0f;
            }
        }

        const float d0 = v.y - v.x;
        const float d1 = v.z - v.y;
        const float d2 = v.w - v.z;
        const float d3 = nx  - v.w;
        const float d4 = ny  - nx;

        // indicator i valid iff i <= TLEN-3 (products d[:-1]*d[1:] has T-2 entries)
        const bool p0 = (d0 * d1 < 0.0f) && (fidx     <= TLEN - 3);
        const bool p1 = (d1 * d2 < 0.0f) && (fidx + 1 <= TLEN - 3);
        const bool p2 = (d2 * d3 < 0.0f) && (fidx + 2 <= TLEN - 3);
        const bool p3 = (d3 * d4 < 0.0f) && (fidx + 3 <= TLEN - 3);

        const unsigned long long m0 = __ballot(p0);
        const unsigned long long m1 = __ballot(p1);
        const unsigned long long m2 = __ballot(p2);
        const unsigned long long m3 = __ballot(p3);

        if (lane == 0) {
            const unsigned int lo = 0xffffffffu;
            const int cntA = __popcll(m0 & lo) + __popcll(m1 & lo)
                           + __popcll(m2 & lo) + __popcll(m3 & lo);
            const int cntB = __popcll(m0 >> 32) + __popcll(m1 >> 32)
                           + __popcll(m2 >> 32) + __popcll(m3 >> 32);
            const int sA = (k << 3) + (wave << 1);   // segment = 128 floats
            wc[sA]     = cntA;
            wc[sA + 1] = cntB;
        }
    }
    __syncthreads();

    if (tid == 0) {
        int acc = 0;
        pseg[0] = 0;
#pragma unroll
        for (int i = 0; i < 32; ++i) {
            acc += wc[i];
            pseg[i + 1] = acc;
        }
    }
    __syncthreads();

    // ---- 57 windows: zc via prefix lookups + boundary corrections, then log formula ----
    if (tid < NW) {
        int scale, off;
        if (tid < 1)       { scale = 0; off = 0;  }
        else if (tid < 4)  { scale = 1; off = 1;  }
        else if (tid < 11) { scale = 2; off = 4;  }
        else if (tid < 26) { scale = 3; off = 11; }
        else               { scale = 4; off = 26; }
        const int w      = TLEN >> scale;       // 4096,2048,1024,512,256
        const int stride = w >> 1;
        const int s      = (tid - off) * stride;
        const int e      = s + w;               // exclusive end, multiple of 128

        // prefix gives sum c[s .. e-1]; window needs sum c[s .. e-3]
        int zc = pseg[e >> 7] - pseg[s >> 7];
        if (e < TLEN) {                          // c[e-2], c[e-1] exist only then
            const float x0 = g[e - 2], x1 = g[e - 1], x2 = g[e], x3 = g[e + 1];
            const float d0 = x1 - x0, d1 = x2 - x1, d2 = x3 - x2;
            zc -= (d0 * d1 < 0.0f) ? 1 : 0;
            zc -= (d1 * d2 < 0.0f) ? 1 : 0;
        }

        const float wf  = (float)w;
        const float num = log10f(wf);
        const float den = num + log10f(wf / (wf + 0.4f * (float)zc));
        out[(size_t)row * NW + tid] = num / den;
    }
}

extern "C" void kernel_launch(void* const* d_in, const int* in_sizes, int n_in,
                              void* d_out, int out_size, void* d_ws, size_t ws_size,
                              hipStream_t stream) {
    const float* x = (const float*)d_in[0];
    float* out = (float*)d_out;
    const int rows = in_sizes[0] / TLEN;         // B*C = 4096
    pfd_kernel<<<dim3(rows), dim3(256), 0, stream>>>(x, out);
}

// Round 3
// 87.681 us; speedup vs baseline: 1.0614x; 1.0614x over previous
//
#include <hip/hip_runtime.h>
#include <math.h>

// FractalFeatureLayer: Petrosian-style fractal dimension over 5 dyadic scales.
// x: (B=64, C=64, T=4096) fp32 -> out: (B, C, 57) fp32.
//
// zc per window = range-sum of indicator c[i] = ((x[i+1]-x[i])*(x[i+2]-x[i+1]) < 0).
// All window boundaries are multiples of 128 -> 128-wide segment sums (ballot
// half-mask popcounts) + 33-entry prefix. Window [s,e) needs sum c[s..e-3];
// the prefix gives c[s..e-1]; the correction bits c[e-2], c[e-1] are lanes 31/63
// of the m2/m3 ballot masks we already computed -> extracted into bc[] during the
// main loop. NO divergent global re-reads anywhere (R3 change vs R2).
//
// Global traffic: exactly 16 coalesced global_load_dwordx4 per thread (64 MB total)
// + 57 floats out per row. Wave-boundary neighbor floats handed off through LDS.

constexpr int TLEN = 4096;
constexpr int NW   = 57;   // 1+3+7+15+31 windows

__global__ __launch_bounds__(256) void pfd_kernel(const float* __restrict__ x,
                                                  float* __restrict__ out) {
    __shared__ float2 bnd[17];  // bnd[k*4+W] = first two floats of wave W's quad in iter k
    __shared__ int    wc[32];   // per-128-float-segment indicator counts
    __shared__ int    bc[33];   // bc[s] = c[128s-2] + c[128s-1]  (s = 1..32)
    __shared__ int    pseg[33]; // exclusive prefix over segments

    const int tid  = threadIdx.x;
    const int row  = blockIdx.x;            // flattened (b*C + c)
    const int wave = tid >> 6;
    const int lane = tid & 63;
    const size_t base = (size_t)row * TLEN;
    const float4* __restrict__ gv = reinterpret_cast<const float4*>(x + base);

    // ---- all 4 loads upfront: 4 global_load_dwordx4 in flight per thread ----
    float4 v[4];
#pragma unroll
    for (int k = 0; k < 4; ++k)
        v[k] = gv[(k << 8) + tid];

    if (tid == 0) bnd[16] = make_float2(0.0f, 0.0f);   // end-of-row (masked anyway)
    if (lane == 0) {
#pragma unroll
        for (int k = 0; k < 4; ++k)
            bnd[(k << 2) + wave] = make_float2(v[k].x, v[k].y);
    }
    __syncthreads();

#pragma unroll
    for (int k = 0; k < 4; ++k) {
        const int q = (k << 8) + tid;       // float4 index within row
        // neighbor floats x[4q+4], x[4q+5]: next lane via shfl; lane 63 via LDS handoff
        float nx = __shfl_down(v[k].x, 1);
        float ny = __shfl_down(v[k].y, 1);
        if (lane == 63) {
            const float2 b = bnd[(k << 2) + wave + 1];  // wave-uniform slot -> broadcast
            nx = b.x; ny = b.y;
        }

        const float d0 = v[k].y - v[k].x;
        const float d1 = v[k].z - v[k].y;
        const float d2 = v[k].w - v[k].z;
        const float d3 = nx - v[k].w;
        const float d4 = ny - nx;

        const bool lastq = (q == TLEN / 4 - 1);         // indicators 4q+2, 4q+3 invalid
        const bool p0 = (d0 * d1 < 0.0f);
        const bool p1 = (d1 * d2 < 0.0f);
        const bool p2 = (d2 * d3 < 0.0f) && !lastq;
        const bool p3 = (d3 * d4 < 0.0f) && !lastq;

        const unsigned long long m0 = __ballot(p0);
        const unsigned long long m1 = __ballot(p1);
        const unsigned long long m2 = __ballot(p2);
        const unsigned long long m3 = __ballot(p3);

        if (lane == 0) {
            const unsigned int lo = 0xffffffffu;
            const int sA = (k << 3) + (wave << 1);      // segment = 128 floats
            wc[sA]     = __popcll(m0 & lo) + __popcll(m1 & lo)
                       + __popcll(m2 & lo) + __popcll(m3 & lo);
            wc[sA + 1] = __popcll(m0 >> 32) + __popcll(m1 >> 32)
                       + __popcll(m2 >> 32) + __popcll(m3 >> 32);
            // boundary-correction bits: segment's last quad sits at lane 31 / lane 63,
            // its position-2/3 indicators are c[128s-2], c[128s-1]
            bc[sA + 1] = (int)((m2 >> 31) & 1ull) + (int)((m3 >> 31) & 1ull);
            bc[sA + 2] = (int)((m2 >> 63) & 1ull) + (int)((m3 >> 63) & 1ull);
        }
    }
    __syncthreads();

    if (tid == 0) {
        int acc = 0;
        pseg[0] = 0;
#pragma unroll
        for (int i = 0; i < 32; ++i) {
            acc += wc[i];
            pseg[i + 1] = acc;
        }
    }
    __syncthreads();

    // ---- 57 windows: zc via prefix + bc correction, then the log formula ----
    if (tid < NW) {
        int scale, off;
        if (tid < 1)       { scale = 0; off = 0;  }
        else if (tid < 4)  { scale = 1; off = 1;  }
        else if (tid < 11) { scale = 2; off = 4;  }
        else if (tid < 26) { scale = 3; off = 11; }
        else               { scale = 4; off = 26; }
        const int w      = TLEN >> scale;       // 4096,2048,1024,512,256
        const int stride = w >> 1;
        const int s      = (tid - off) * stride;
        const int e      = s + w;               // exclusive end, multiple of 128

        int zc = pseg[e >> 7] - pseg[s >> 7];
        if (e < TLEN) zc -= bc[e >> 7];          // subtract c[e-2] + c[e-1]

        const float wf  = (float)w;
        const float num = log10f(wf);
        const float den = num + log10f(wf / (wf + 0.4f * (float)zc));
        out[(size_t)row * NW + tid] = num / den;
    }
}

extern "C" void kernel_launch(void* const* d_in, const int* in_sizes, int n_in,
                              void* d_out, int out_size, void* d_ws, size_t ws_size,
                              hipStream_t stream) {
    const float* x = (const float*)d_in[0];
    float* out = (float*)d_out;
    const int rows = in_sizes[0] / TLEN;         // B*C = 4096
    pfd_kernel<<<dim3(rows), dim3(256), 0, stream>>>(x, out);
}